// Round 1
// baseline (145.708 us; speedup 1.0000x reference)
//
#include <hip/hip_runtime.h>

// ---------------------------------------------------------------------------
// AI4Urban one-timestep NS solver on 64x128x256, f32.
// Exact simplifications used (mathematically identical to reference):
//  - pg_vector(...) == 7-pt Laplacian of the BC-padded field (k_uu is all-ones,
//    conv(ones,lap)==0 exactly in f32).
//  - MG p-update: p_new = p_old - w + r0/6  (r0 = lap(pp)-b, diag=-6).
//  - prolongation fused as coarse[i>>1] reads.
// ---------------------------------------------------------------------------

constexpr int NZ = 64, NY = 128, NX = 256;
constexpr int NTOT = NZ * NY * NX;
constexpr float DT  = 0.01f;
constexpr float RE  = 0.001f;
constexpr float UBC = -1.0f;
constexpr float DIAG = -6.0f;

__device__ __forceinline__ int idx3(int z, int y, int x) {
    return (z * NY + y) * NX + x;
}

// bc_u: zero halo, except padded x==-1 face -> UBC (only reached with valid y,z)
__device__ __forceinline__ float ld_u(const float* __restrict__ f, int z, int y, int x) {
    if (x < 0) return UBC;
    if (x >= NX || (unsigned)y >= (unsigned)NY || (unsigned)z >= (unsigned)NZ) return 0.f;
    return f[idx3(z, y, x)];
}
// zero-pad BC
__device__ __forceinline__ float ld_0(const float* __restrict__ f, int z, int y, int x) {
    if ((unsigned)x >= (unsigned)NX || (unsigned)y >= (unsigned)NY || (unsigned)z >= (unsigned)NZ) return 0.f;
    return f[idx3(z, y, x)];
}
// edge-replicate BC (Neumann)
__device__ __forceinline__ float ld_p(const float* __restrict__ f, int z, int y, int x) {
    x = x < 0 ? 0 : (x > NX - 1 ? NX - 1 : x);
    y = y < 0 ? 0 : (y > NY - 1 ? NY - 1 : y);
    z = z < 0 ? 0 : (z > NZ - 1 ? NZ - 1 : z);
    return f[idx3(z, y, x)];
}

// K1: first solid_body
__global__ __launch_bounds__(256) void k_sb(
    const float* __restrict__ u, const float* __restrict__ v,
    const float* __restrict__ w, const float* __restrict__ sg,
    float* __restrict__ u1, float* __restrict__ v1, float* __restrict__ w1) {
    int i = blockIdx.x * 256 + threadIdx.x;
    float s = 1.0f + DT * sg[i];
    u1[i] = u[i] / s;
    v1[i] = v[i] / s;
    w1[i] = w[i] / s;
}

// K2: momentum predictor -> b_u, b_v, b_w (includes second solid_body)
__global__ __launch_bounds__(256) void k_predict(
    const float* __restrict__ u1, const float* __restrict__ v1, const float* __restrict__ w1,
    const float* __restrict__ p, const float* __restrict__ sg,
    float* __restrict__ bu, float* __restrict__ bv, float* __restrict__ bw) {
    int x = threadIdx.x, y = blockIdx.x, z = blockIdx.y;
    int c = idx3(z, y, x);
    float uc = u1[c], vc = v1[c], wc = w1[c];

    float uxm = ld_u(u1, z, y, x - 1), uxp = ld_u(u1, z, y, x + 1);
    float uym = ld_0(u1, z, y - 1, x), uyp = ld_0(u1, z, y + 1, x);
    float uzm = ld_0(u1, z - 1, y, x), uzp = ld_0(u1, z + 1, y, x);

    float vxm = ld_0(v1, z, y, x - 1), vxp = ld_0(v1, z, y, x + 1);
    float vym = ld_0(v1, z, y - 1, x), vyp = ld_0(v1, z, y + 1, x);
    float vzm = ld_0(v1, z - 1, y, x), vzp = ld_0(v1, z + 1, y, x);

    float wxm = ld_0(w1, z, y, x - 1), wxp = ld_0(w1, z, y, x + 1);
    float wym = ld_0(w1, z, y - 1, x), wyp = ld_0(w1, z, y + 1, x);
    float wzm = ld_0(w1, z - 1, y, x), wzp = ld_0(w1, z + 1, y, x);

    float dpx = 0.5f * (ld_p(p, z, y, x + 1) - ld_p(p, z, y, x - 1));
    float dpy = 0.5f * (ld_p(p, z, y + 1, x) - ld_p(p, z, y - 1, x));
    float dpz = 0.5f * (ld_p(p, z + 1, y, x) - ld_p(p, z - 1, y, x));

    float lap_u = uxm + uxp + uym + uyp + uzm + uzp - 6.f * uc;
    float lap_v = vxm + vxp + vym + vyp + vzm + vzp - 6.f * vc;
    float lap_w = wxm + wxp + wym + wyp + wzm + wzp - 6.f * wc;

    float s = 1.0f + DT * sg[c];
    float bun = uc + 0.5f * (RE * lap_u * DT
                             - uc * (0.5f * (uxp - uxm)) * DT
                             - vc * (0.5f * (uyp - uym)) * DT
                             - wc * (0.5f * (uzp - uzm)) * DT) - dpx * DT;
    float bvn = vc + 0.5f * (RE * lap_v * DT
                             - uc * (0.5f * (vxp - vxm)) * DT
                             - vc * (0.5f * (vyp - vym)) * DT
                             - wc * (0.5f * (vzp - vzm)) * DT) - dpy * DT;
    float bwn = wc + 0.5f * (RE * lap_w * DT
                             - uc * (0.5f * (wxp - wxm)) * DT
                             - vc * (0.5f * (wyp - wym)) * DT
                             - wc * (0.5f * (wzp - wzm)) * DT) - dpz * DT;
    bu[c] = bun / s;
    bv[c] = bvn / s;
    bw[c] = bwn / s;
}

// K3: corrector -> u2,v2,w2 (in-place over u1,v1,w1; only center reads of u1)
__global__ __launch_bounds__(256) void k_correct(
    const float* __restrict__ u1, const float* __restrict__ v1, const float* __restrict__ w1,
    const float* __restrict__ bu, const float* __restrict__ bv, const float* __restrict__ bw,
    const float* __restrict__ p, const float* __restrict__ sg,
    float* __restrict__ u2, float* __restrict__ v2, float* __restrict__ w2) {
    int x = threadIdx.x, y = blockIdx.x, z = blockIdx.y;
    int c = idx3(z, y, x);
    float buc = bu[c], bvc = bv[c], bwc = bw[c];

    float uxm = ld_u(bu, z, y, x - 1), uxp = ld_u(bu, z, y, x + 1);
    float uym = ld_0(bu, z, y - 1, x), uyp = ld_0(bu, z, y + 1, x);
    float uzm = ld_0(bu, z - 1, y, x), uzp = ld_0(bu, z + 1, y, x);

    float vxm = ld_0(bv, z, y, x - 1), vxp = ld_0(bv, z, y, x + 1);
    float vym = ld_0(bv, z, y - 1, x), vyp = ld_0(bv, z, y + 1, x);
    float vzm = ld_0(bv, z - 1, y, x), vzp = ld_0(bv, z + 1, y, x);

    float wxm = ld_0(bw, z, y, x - 1), wxp = ld_0(bw, z, y, x + 1);
    float wym = ld_0(bw, z, y - 1, x), wyp = ld_0(bw, z, y + 1, x);
    float wzm = ld_0(bw, z - 1, y, x), wzp = ld_0(bw, z + 1, y, x);

    float dpx = 0.5f * (ld_p(p, z, y, x + 1) - ld_p(p, z, y, x - 1));
    float dpy = 0.5f * (ld_p(p, z, y + 1, x) - ld_p(p, z, y - 1, x));
    float dpz = 0.5f * (ld_p(p, z + 1, y, x) - ld_p(p, z - 1, y, x));

    float lap_u = uxm + uxp + uym + uyp + uzm + uzp - 6.f * buc;
    float lap_v = vxm + vxp + vym + vyp + vzm + vzp - 6.f * bvc;
    float lap_w = wxm + wxp + wym + wyp + wzm + wzp - 6.f * bwc;

    float s = 1.0f + DT * sg[c];
    float un = u1[c] + RE * lap_u * DT
               - buc * (0.5f * (uxp - uxm)) * DT
               - bvc * (0.5f * (uyp - uym)) * DT
               - bwc * (0.5f * (uzp - uzm)) * DT - dpx * DT;
    float vn = v1[c] + RE * lap_v * DT
               - buc * (0.5f * (vxp - vxm)) * DT
               - bvc * (0.5f * (vyp - vym)) * DT
               - bwc * (0.5f * (vzp - vzm)) * DT - dpy * DT;
    float wn = w1[c] + RE * lap_w * DT
               - buc * (0.5f * (wxp - wxm)) * DT
               - bvc * (0.5f * (wyp - wym)) * DT
               - bwc * (0.5f * (wzp - wzm)) * DT - dpz * DT;
    u2[c] = un / s;
    v2[c] = vn / s;
    w2[c] = wn / s;
}

// K4: MG right-hand side b = -div(velocity)/DT
__global__ __launch_bounds__(256) void k_div(
    const float* __restrict__ u2, const float* __restrict__ v2, const float* __restrict__ w2,
    float* __restrict__ b) {
    int x = threadIdx.x, y = blockIdx.x, z = blockIdx.y;
    int c = idx3(z, y, x);
    float dxu = 0.5f * (ld_u(u2, z, y, x + 1) - ld_u(u2, z, y, x - 1));
    float dyv = 0.5f * (ld_0(v2, z, y + 1, x) - ld_0(v2, z, y - 1, x));
    float dzw = 0.5f * (ld_0(w2, z + 1, y, x) - ld_0(w2, z - 1, y, x));
    b[c] = -(dxu + dyv + dzw) / DT;
}

// K5: residual r0 = lap_Neumann(p) - b
__global__ __launch_bounds__(256) void k_resid(
    const float* __restrict__ p, const float* __restrict__ b, float* __restrict__ r0) {
    int x = threadIdx.x, y = blockIdx.x, z = blockIdx.y;
    int c = idx3(z, y, x);
    float pc = p[c];
    float lap = ld_p(p, z, y, x - 1) + ld_p(p, z, y, x + 1)
              + ld_p(p, z, y - 1, x) + ld_p(p, z, y + 1, x)
              + ld_p(p, z - 1, y, x) + ld_p(p, z + 1, y, x) - 6.f * pc;
    r0[c] = lap - b[c];
}

// K6: 2x2x2 full-weighting restriction (stride 2). out dims from launch config:
// block.x = Xc, grid.x = Yc, grid.y = Zc
__global__ void k_restrict(const float* __restrict__ in, float* __restrict__ out) {
    int Xc = blockDim.x, Yc = gridDim.x;
    int x = threadIdx.x, y = blockIdx.x, z = blockIdx.y;
    int Xf = Xc << 1;
    size_t zstr = (size_t)(Yc << 1) * Xf;
    size_t base = ((size_t)(2 * z) * (Yc << 1) + 2 * y) * Xf + 2 * x;
    float s = in[base] + in[base + 1] + in[base + Xf] + in[base + Xf + 1]
            + in[base + zstr] + in[base + zstr + 1] + in[base + zstr + Xf] + in[base + zstr + Xf + 1];
    out[((size_t)z * Yc + y) * Xc + x] = 0.125f * s;
}

// coarsest-level smoothing from w=0:  A = r4 / diag
__global__ void k_scaleA(const float* __restrict__ r4, float* __restrict__ A) {
    int i = blockIdx.x * 256 + threadIdx.x;
    if (i < 512) A[i] = r4[i] / DIAG;
}

// prolonged coarse read with zero BC at the fine level
__device__ __forceinline__ float wprol(const float* __restrict__ Wc,
                                       int zz, int yy, int xx, int Z, int Y, int X) {
    if ((unsigned)xx >= (unsigned)X || (unsigned)yy >= (unsigned)Y || (unsigned)zz >= (unsigned)Z) return 0.f;
    return Wc[(((zz >> 1) * (Y >> 1)) + (yy >> 1)) * (X >> 1) + (xx >> 1)];
}

// K_up: one V-cycle up-level: out = prol(Wc) - lap0(prol(Wc))/diag + r/diag
// dims from launch config: block.x = X, grid.x = Y, grid.y = Z
__global__ void k_up(const float* __restrict__ Wc, const float* __restrict__ r,
                     float* __restrict__ out) {
    int X = blockDim.x, Y = gridDim.x, Z = gridDim.y;
    int x = threadIdx.x, y = blockIdx.x, z = blockIdx.y;
    float wcn = Wc[(((z >> 1) * (Y >> 1)) + (y >> 1)) * (X >> 1) + (x >> 1)];
    float lap = wprol(Wc, z - 1, y, x, Z, Y, X) + wprol(Wc, z + 1, y, x, Z, Y, X)
              + wprol(Wc, z, y - 1, x, Z, Y, X) + wprol(Wc, z, y + 1, x, Z, Y, X)
              + wprol(Wc, z, y, x - 1, Z, Y, X) + wprol(Wc, z, y, x + 1, Z, Y, X)
              - 6.f * wcn;
    int i = (z * Y + y) * X + x;
    out[i] = wcn - lap / DIAG + r[i] / DIAG;
}

// K7: p update: p_new = p_old - prol(D) + r0/6 ; optionally emit w_mg = prol(D)
__global__ __launch_bounds__(256) void k_pup(
    const float* __restrict__ pin, const float* __restrict__ D,
    const float* __restrict__ r0, float* __restrict__ pout, float* __restrict__ wmg) {
    int x = threadIdx.x, y = blockIdx.x, z = blockIdx.y;
    int c = idx3(z, y, x);
    float wv = D[(((z >> 1) * (NY >> 1)) + (y >> 1)) * (NX >> 1) + (x >> 1)];
    float pv = pin[c] - wv + r0[c] / 6.0f;
    pout[c] = pv;
    if (wmg) wmg[c] = wv;
}

// K8: final projection + solid_body
__global__ __launch_bounds__(256) void k_final(
    const float* __restrict__ p,
    const float* __restrict__ u2, const float* __restrict__ v2, const float* __restrict__ w2,
    const float* __restrict__ sg,
    float* __restrict__ uo, float* __restrict__ vo, float* __restrict__ wo) {
    int x = threadIdx.x, y = blockIdx.x, z = blockIdx.y;
    int c = idx3(z, y, x);
    float dpx = 0.5f * (ld_p(p, z, y, x + 1) - ld_p(p, z, y, x - 1));
    float dpy = 0.5f * (ld_p(p, z, y + 1, x) - ld_p(p, z, y - 1, x));
    float dpz = 0.5f * (ld_p(p, z + 1, y, x) - ld_p(p, z - 1, y, x));
    float s = 1.0f + DT * sg[c];
    uo[c] = (u2[c] - dpx * DT) / s;
    vo[c] = (v2[c] - dpy * DT) / s;
    wo[c] = (w2[c] - dpz * DT) / s;
}

extern "C" void kernel_launch(void* const* d_in, const int* in_sizes, int n_in,
                              void* d_out, int out_size, void* d_ws, size_t ws_size,
                              hipStream_t stream) {
    const float* in_u  = (const float*)d_in[0];
    const float* in_v  = (const float*)d_in[1];
    const float* in_w  = (const float*)d_in[2];
    const float* in_p  = (const float*)d_in[3];
    const float* in_sg = (const float*)d_in[4];
    // d_in[5..10]: stencil weights (fixed by setup_inputs, hardcoded above)
    // d_in[11], d_in[12]: iteration=2, nlevel=6 (hardcoded)

    float* out   = (float*)d_out;
    float* O_u   = out;
    float* O_v   = out + (size_t)NTOT;
    float* O_w   = out + (size_t)2 * NTOT;
    float* O_p   = out + (size_t)3 * NTOT;
    float* O_wmg = out + (size_t)4 * NTOT;
    float* O_r   = out + (size_t)5 * NTOT;   // 512 elems

    float* ws = (float*)d_ws;
    float* A0 = ws;                      // u1 -> u2
    float* A1 = ws + (size_t)NTOT;       // v1 -> v2
    float* A2 = ws + (size_t)2 * NTOT;   // w1 -> w2

    // Coarse pyramid pool lives in O_v (free between K3 and K8); r0 in O_u; b in O_wmg.
    float* r1 = O_v;                 // 32*64*128 = 262144
    float* r2 = O_v + 262144;        // 16*32*64  = 32768
    float* r3 = O_v + 294912;        // 8*16*32   = 4096
    float* Ab = O_v + 299008;        // 4*8*16    = 512
    float* Bb = O_v + 299520;        // 8*16*32   = 4096
    float* Cb = O_v + 303616;        // 16*32*64  = 32768
    float* Db = O_v + 336384;        // 32*64*128 = 262144
    float* r0 = O_u;
    float* bb = O_wmg;

    dim3 gF(NY, NZ);                 // fine grid: block = NX
    k_sb<<<dim3(NTOT / 256), dim3(256), 0, stream>>>(in_u, in_v, in_w, in_sg, A0, A1, A2);
    k_predict<<<gF, dim3(NX), 0, stream>>>(A0, A1, A2, in_p, in_sg, O_u, O_v, O_w);
    k_correct<<<gF, dim3(NX), 0, stream>>>(A0, A1, A2, O_u, O_v, O_w, in_p, in_sg, A0, A1, A2);
    k_div<<<gF, dim3(NX), 0, stream>>>(A0, A1, A2, bb);

    for (int iter = 0; iter < 2; ++iter) {
        const float* pcur = iter ? O_p : in_p;
        k_resid<<<gF, dim3(NX), 0, stream>>>(pcur, bb, r0);
        k_restrict<<<dim3(64, 32), dim3(128), 0, stream>>>(r0, r1);
        k_restrict<<<dim3(32, 16), dim3(64),  0, stream>>>(r1, r2);
        k_restrict<<<dim3(16, 8),  dim3(32),  0, stream>>>(r2, r3);
        k_restrict<<<dim3(8, 4),   dim3(16),  0, stream>>>(r3, O_r);
        k_scaleA<<<dim3(2), dim3(256), 0, stream>>>(O_r, Ab);
        k_up<<<dim3(16, 8),  dim3(32),  0, stream>>>(Ab, r3, Bb);
        k_up<<<dim3(32, 16), dim3(64),  0, stream>>>(Bb, r2, Cb);
        k_up<<<dim3(64, 32), dim3(128), 0, stream>>>(Cb, r1, Db);
        k_pup<<<gF, dim3(NX), 0, stream>>>(pcur, Db, r0, O_p, iter ? O_wmg : nullptr);
    }

    k_final<<<gF, dim3(NX), 0, stream>>>(O_p, A0, A1, A2, in_sg, O_u, O_v, O_w);
}

// Round 2
// 123.941 us; speedup vs baseline: 1.1756x; 1.1756x over previous
//
#include <hip/hip_runtime.h>

// ---------------------------------------------------------------------------
// AI4Urban one-timestep NS solver on 64x128x256, f32.  Round 2: fusion.
//  - solid_body fused into predictor (recompute u1 at stencil points) and
//    corrector (center-only recompute).
//  - div + first residual fused; p-update + next residual fused (p_new is
//    pointwise in p_old, D, r0 -> neighbors recomputed from cached reads).
//  - coarse MG pyramid (levels 2..4) fused: one down kernel (r1->r2,r3,r4 via
//    LDS) and one up kernel (A=r4/diag, B in LDS, C out) per iteration.
// 14 dispatches total.
// ---------------------------------------------------------------------------

constexpr int NZ = 64, NY = 128, NX = 256;
constexpr int NTOT = NZ * NY * NX;
constexpr float DT  = 0.01f;
constexpr float RE  = 0.001f;
constexpr float UBC = -1.0f;
constexpr float DIAG = -6.0f;

__device__ __forceinline__ int idx3(int z, int y, int x) {
    return (z * NY + y) * NX + x;
}

// bc_u: zero halo, except padded x==-1 face -> UBC
__device__ __forceinline__ float ld_u(const float* __restrict__ f, int z, int y, int x) {
    if (x < 0) return UBC;
    if (x >= NX || (unsigned)y >= (unsigned)NY || (unsigned)z >= (unsigned)NZ) return 0.f;
    return f[idx3(z, y, x)];
}
// zero-pad BC
__device__ __forceinline__ float ld_0(const float* __restrict__ f, int z, int y, int x) {
    if ((unsigned)x >= (unsigned)NX || (unsigned)y >= (unsigned)NY || (unsigned)z >= (unsigned)NZ) return 0.f;
    return f[idx3(z, y, x)];
}
// edge-replicate BC (Neumann)
__device__ __forceinline__ float ld_p(const float* __restrict__ f, int z, int y, int x) {
    x = x < 0 ? 0 : (x > NX - 1 ? NX - 1 : x);
    y = y < 0 ? 0 : (y > NY - 1 ? NY - 1 : y);
    z = z < 0 ? 0 : (z > NZ - 1 ? NZ - 1 : z);
    return f[idx3(z, y, x)];
}

// K1: predictor with solid_body fused (u1 = u/(1+DT*sg) recomputed per point)
__global__ __launch_bounds__(256) void k_predict(
    const float* __restrict__ u, const float* __restrict__ v, const float* __restrict__ w,
    const float* __restrict__ p, const float* __restrict__ sg,
    float* __restrict__ bu, float* __restrict__ bv, float* __restrict__ bw) {
    int x = threadIdx.x, y = blockIdx.x, z = blockIdx.y;
    int c = idx3(z, y, x);
    float inv = 1.f / (1.f + DT * sg[c]);
    float uc = u[c] * inv, vc = v[c] * inv, wc = w[c] * inv;

    float uxm, vxm, wxm, uxp, vxp, wxp, uym, vym, wym, uyp, vyp, wyp, uzm, vzm, wzm, uzp, vzp, wzp;
    if (x == 0) { uxm = UBC; vxm = 0.f; wxm = 0.f; }
    else { int i = c - 1; float iv = 1.f / (1.f + DT * sg[i]); uxm = u[i]*iv; vxm = v[i]*iv; wxm = w[i]*iv; }
    if (x == NX - 1) { uxp = vxp = wxp = 0.f; }
    else { int i = c + 1; float iv = 1.f / (1.f + DT * sg[i]); uxp = u[i]*iv; vxp = v[i]*iv; wxp = w[i]*iv; }
    if (y == 0) { uym = vym = wym = 0.f; }
    else { int i = c - NX; float iv = 1.f / (1.f + DT * sg[i]); uym = u[i]*iv; vym = v[i]*iv; wym = w[i]*iv; }
    if (y == NY - 1) { uyp = vyp = wyp = 0.f; }
    else { int i = c + NX; float iv = 1.f / (1.f + DT * sg[i]); uyp = u[i]*iv; vyp = v[i]*iv; wyp = w[i]*iv; }
    if (z == 0) { uzm = vzm = wzm = 0.f; }
    else { int i = c - NX*NY; float iv = 1.f / (1.f + DT * sg[i]); uzm = u[i]*iv; vzm = v[i]*iv; wzm = w[i]*iv; }
    if (z == NZ - 1) { uzp = vzp = wzp = 0.f; }
    else { int i = c + NX*NY; float iv = 1.f / (1.f + DT * sg[i]); uzp = u[i]*iv; vzp = v[i]*iv; wzp = w[i]*iv; }

    float dpx = 0.5f * (ld_p(p, z, y, x + 1) - ld_p(p, z, y, x - 1));
    float dpy = 0.5f * (ld_p(p, z, y + 1, x) - ld_p(p, z, y - 1, x));
    float dpz = 0.5f * (ld_p(p, z + 1, y, x) - ld_p(p, z - 1, y, x));

    float lap_u = uxm + uxp + uym + uyp + uzm + uzp - 6.f * uc;
    float lap_v = vxm + vxp + vym + vyp + vzm + vzp - 6.f * vc;
    float lap_w = wxm + wxp + wym + wyp + wzm + wzp - 6.f * wc;

    float bun = uc + 0.5f * (RE * lap_u * DT
                             - uc * (0.5f * (uxp - uxm)) * DT
                             - vc * (0.5f * (uyp - uym)) * DT
                             - wc * (0.5f * (uzp - uzm)) * DT) - dpx * DT;
    float bvn = vc + 0.5f * (RE * lap_v * DT
                             - uc * (0.5f * (vxp - vxm)) * DT
                             - vc * (0.5f * (vyp - vym)) * DT
                             - wc * (0.5f * (vzp - vzm)) * DT) - dpy * DT;
    float bwn = wc + 0.5f * (RE * lap_w * DT
                             - uc * (0.5f * (wxp - wxm)) * DT
                             - vc * (0.5f * (wyp - wym)) * DT
                             - wc * (0.5f * (wzp - wzm)) * DT) - dpz * DT;
    bu[c] = bun * inv;   // second solid_body: same sigma, same s
    bv[c] = bvn * inv;
    bw[c] = bwn * inv;
}

// K2: corrector; u1 center recomputed from raw inputs
__global__ __launch_bounds__(256) void k_correct(
    const float* __restrict__ u, const float* __restrict__ v, const float* __restrict__ w,
    const float* __restrict__ sg,
    const float* __restrict__ bu, const float* __restrict__ bv, const float* __restrict__ bw,
    const float* __restrict__ p,
    float* __restrict__ u2, float* __restrict__ v2, float* __restrict__ w2) {
    int x = threadIdx.x, y = blockIdx.x, z = blockIdx.y;
    int c = idx3(z, y, x);
    float inv = 1.f / (1.f + DT * sg[c]);
    float u1c = u[c] * inv, v1c = v[c] * inv, w1c = w[c] * inv;
    float buc = bu[c], bvc = bv[c], bwc = bw[c];

    float uxm = ld_u(bu, z, y, x - 1), uxp = ld_u(bu, z, y, x + 1);
    float uym = ld_0(bu, z, y - 1, x), uyp = ld_0(bu, z, y + 1, x);
    float uzm = ld_0(bu, z - 1, y, x), uzp = ld_0(bu, z + 1, y, x);

    float vxm = ld_0(bv, z, y, x - 1), vxp = ld_0(bv, z, y, x + 1);
    float vym = ld_0(bv, z, y - 1, x), vyp = ld_0(bv, z, y + 1, x);
    float vzm = ld_0(bv, z - 1, y, x), vzp = ld_0(bv, z + 1, y, x);

    float wxm = ld_0(bw, z, y, x - 1), wxp = ld_0(bw, z, y, x + 1);
    float wym = ld_0(bw, z, y - 1, x), wyp = ld_0(bw, z, y + 1, x);
    float wzm = ld_0(bw, z - 1, y, x), wzp = ld_0(bw, z + 1, y, x);

    float dpx = 0.5f * (ld_p(p, z, y, x + 1) - ld_p(p, z, y, x - 1));
    float dpy = 0.5f * (ld_p(p, z, y + 1, x) - ld_p(p, z, y - 1, x));
    float dpz = 0.5f * (ld_p(p, z + 1, y, x) - ld_p(p, z - 1, y, x));

    float lap_u = uxm + uxp + uym + uyp + uzm + uzp - 6.f * buc;
    float lap_v = vxm + vxp + vym + vyp + vzm + vzp - 6.f * bvc;
    float lap_w = wxm + wxp + wym + wyp + wzm + wzp - 6.f * bwc;

    float un = u1c + RE * lap_u * DT
               - buc * (0.5f * (uxp - uxm)) * DT
               - bvc * (0.5f * (uyp - uym)) * DT
               - bwc * (0.5f * (uzp - uzm)) * DT - dpx * DT;
    float vn = v1c + RE * lap_v * DT
               - buc * (0.5f * (vxp - vxm)) * DT
               - bvc * (0.5f * (vyp - vym)) * DT
               - bwc * (0.5f * (vzp - vzm)) * DT - dpy * DT;
    float wn = w1c + RE * lap_w * DT
               - buc * (0.5f * (wxp - wxm)) * DT
               - bvc * (0.5f * (wyp - wym)) * DT
               - bwc * (0.5f * (wzp - wzm)) * DT - dpz * DT;
    u2[c] = un * inv;
    v2[c] = vn * inv;
    w2[c] = wn * inv;
}

// K3: b = -div(vel)/DT  AND  r0 = lap_Neumann(p) - b
__global__ __launch_bounds__(256) void k_divresid(
    const float* __restrict__ u2, const float* __restrict__ v2, const float* __restrict__ w2,
    const float* __restrict__ p, float* __restrict__ bO, float* __restrict__ r0) {
    int x = threadIdx.x, y = blockIdx.x, z = blockIdx.y;
    int c = idx3(z, y, x);
    float dxu = 0.5f * (ld_u(u2, z, y, x + 1) - ld_u(u2, z, y, x - 1));
    float dyv = 0.5f * (ld_0(v2, z, y + 1, x) - ld_0(v2, z, y - 1, x));
    float dzw = 0.5f * (ld_0(w2, z + 1, y, x) - ld_0(w2, z - 1, y, x));
    float bval = -(dxu + dyv + dzw) / DT;
    float lap = ld_p(p, z, y, x - 1) + ld_p(p, z, y, x + 1)
              + ld_p(p, z, y - 1, x) + ld_p(p, z, y + 1, x)
              + ld_p(p, z - 1, y, x) + ld_p(p, z + 1, y, x) - 6.f * p[c];
    bO[c] = bval;
    r0[c] = lap - bval;
}

// K4: 2x2x2 restriction, generic (block.x = Xc, grid.x = Yc, grid.y = Zc)
__global__ void k_restrict(const float* __restrict__ in, float* __restrict__ out) {
    int Xc = blockDim.x, Yc = gridDim.x;
    int x = threadIdx.x, y = blockIdx.x, z = blockIdx.y;
    int Xf = Xc << 1;
    size_t zstr = (size_t)(Yc << 1) * Xf;
    size_t base = ((size_t)(2 * z) * (Yc << 1) + 2 * y) * Xf + 2 * x;
    float s = in[base] + in[base + 1] + in[base + Xf] + in[base + Xf + 1]
            + in[base + zstr] + in[base + zstr + 1] + in[base + zstr + Xf] + in[base + zstr + Xf + 1];
    out[((size_t)z * Yc + y) * Xc + x] = 0.125f * s;
}

// K5: fused coarse down-chain r1(32,64,128) -> r2(16,32,64), r3(8,16,32), r4(4,8,16)
__global__ __launch_bounds__(512) void k_cdown(const float* __restrict__ r1,
    float* __restrict__ r2, float* __restrict__ r3, float* __restrict__ r4) {
    __shared__ float l2[4][8][16];
    __shared__ float l3[2][4][8];
    int tid = threadIdx.x;
    int bx = blockIdx.x, by = blockIdx.y, bz = blockIdx.z;
    int tx = tid & 15, ty = (tid >> 4) & 7, tz = tid >> 7;
    int x2 = bx * 16 + tx, y2 = by * 8 + ty, z2 = bz * 4 + tz;
    const int X1 = 128, Y1 = 64;
    size_t zs = (size_t)Y1 * X1;
    size_t b0 = ((size_t)(2 * z2) * Y1 + 2 * y2) * X1 + 2 * x2;
    float s = r1[b0] + r1[b0 + 1] + r1[b0 + X1] + r1[b0 + X1 + 1]
            + r1[b0 + zs] + r1[b0 + zs + 1] + r1[b0 + zs + X1] + r1[b0 + zs + X1 + 1];
    float v2 = 0.125f * s;
    l2[tz][ty][tx] = v2;
    r2[((z2 * 32) + y2) * 64 + x2] = v2;
    __syncthreads();
    if (tid < 64) {
        int tx3 = tid & 7, ty3 = (tid >> 3) & 3, tz3 = tid >> 5;
        float s3 = l2[2*tz3][2*ty3][2*tx3]     + l2[2*tz3][2*ty3][2*tx3+1]
                 + l2[2*tz3][2*ty3+1][2*tx3]   + l2[2*tz3][2*ty3+1][2*tx3+1]
                 + l2[2*tz3+1][2*ty3][2*tx3]   + l2[2*tz3+1][2*ty3][2*tx3+1]
                 + l2[2*tz3+1][2*ty3+1][2*tx3] + l2[2*tz3+1][2*ty3+1][2*tx3+1];
        float v3 = 0.125f * s3;
        l3[tz3][ty3][tx3] = v3;
        int z3 = bz * 2 + tz3, y3 = by * 4 + ty3, x3 = bx * 8 + tx3;
        r3[((z3 * 16) + y3) * 32 + x3] = v3;
    }
    __syncthreads();
    if (tid < 8) {
        int tx4 = tid & 3, ty4 = tid >> 2;
        float s4 = l3[0][2*ty4][2*tx4]   + l3[0][2*ty4][2*tx4+1]
                 + l3[0][2*ty4+1][2*tx4] + l3[0][2*ty4+1][2*tx4+1]
                 + l3[1][2*ty4][2*tx4]   + l3[1][2*ty4][2*tx4+1]
                 + l3[1][2*ty4+1][2*tx4] + l3[1][2*ty4+1][2*tx4+1];
        int z4 = bz, y4 = by * 2 + ty4, x4 = bx * 4 + tx4;
        r4[((z4 * 8) + y4) * 16 + x4] = 0.125f * s4;
    }
}

// prolonged-A read with bc_cw zero at level-3 bounds; A = r4/diag
__device__ __forceinline__ float a4p(const float* __restrict__ r4, int z3, int y3, int x3) {
    if ((unsigned)z3 >= 8u || (unsigned)y3 >= 16u || (unsigned)x3 >= 32u) return 0.f;
    return r4[(((z3 >> 1) * 8) + (y3 >> 1)) * 16 + (x3 >> 1)] / DIAG;
}

// K6: fused coarse up-chain: A=r4/diag -> B(8,16,32) in LDS -> C(16,32,64) out
__global__ __launch_bounds__(512) void k_cup(const float* __restrict__ r4,
    const float* __restrict__ r3, const float* __restrict__ r2, float* __restrict__ C) {
    __shared__ float Bl[4][6][10];
    int tid = threadIdx.x;
    int bx = blockIdx.x, by = blockIdx.y, bz = blockIdx.z;
    int Bz0 = bz * 2 - 1, By0 = by * 4 - 1, Bx0 = bx * 8 - 1;
    if (tid < 240) {
        int lx = tid % 10, ly = (tid / 10) % 6, lz = tid / 60;
        int z3 = Bz0 + lz, y3 = By0 + ly, x3 = Bx0 + lx;
        float val = 0.f;
        if ((unsigned)z3 < 8u && (unsigned)y3 < 16u && (unsigned)x3 < 32u) {
            float wcn = r4[(((z3 >> 1) * 8) + (y3 >> 1)) * 16 + (x3 >> 1)] / DIAG;
            float lap = a4p(r4, z3 - 1, y3, x3) + a4p(r4, z3 + 1, y3, x3)
                      + a4p(r4, z3, y3 - 1, x3) + a4p(r4, z3, y3 + 1, x3)
                      + a4p(r4, z3, y3, x3 - 1) + a4p(r4, z3, y3, x3 + 1) - 6.f * wcn;
            val = wcn - lap / DIAG + r3[((z3 * 16) + y3) * 32 + x3] / DIAG;
        }
        Bl[lz][ly][lx] = val;
    }
    __syncthreads();
    int tx = tid & 15, ty = (tid >> 4) & 7, tz = tid >> 7;
    int x2 = bx * 16 + tx, y2 = by * 8 + ty, z2 = bz * 4 + tz;   // level-2 coords
    auto bl = [&](int z, int y, int x) -> float {
        if ((unsigned)z >= 16u || (unsigned)y >= 32u || (unsigned)x >= 64u) return 0.f;
        return Bl[(z >> 1) - Bz0][(y >> 1) - By0][(x >> 1) - Bx0];
    };
    float wB = Bl[(z2 >> 1) - Bz0][(y2 >> 1) - By0][(x2 >> 1) - Bx0];
    float lap = bl(z2 - 1, y2, x2) + bl(z2 + 1, y2, x2)
              + bl(z2, y2 - 1, x2) + bl(z2, y2 + 1, x2)
              + bl(z2, y2, x2 - 1) + bl(z2, y2, x2 + 1) - 6.f * wB;
    int i = ((z2 * 32) + y2) * 64 + x2;
    C[i] = wB - lap / DIAG + r2[i] / DIAG;
}

// prolonged coarse read with zero BC at the fine level
__device__ __forceinline__ float wprol(const float* __restrict__ Wc,
                                       int zz, int yy, int xx, int Z, int Y, int X) {
    if ((unsigned)xx >= (unsigned)X || (unsigned)yy >= (unsigned)Y || (unsigned)zz >= (unsigned)Z) return 0.f;
    return Wc[(((zz >> 1) * (Y >> 1)) + (yy >> 1)) * (X >> 1) + (xx >> 1)];
}

// K7: level-1 up: out = prol(Wc) - lap(prol(Wc))/diag + r/diag   (generic dims)
__global__ void k_up(const float* __restrict__ Wc, const float* __restrict__ r,
                     float* __restrict__ out) {
    int X = blockDim.x, Y = gridDim.x, Z = gridDim.y;
    int x = threadIdx.x, y = blockIdx.x, z = blockIdx.y;
    float wcn = Wc[(((z >> 1) * (Y >> 1)) + (y >> 1)) * (X >> 1) + (x >> 1)];
    float lap = wprol(Wc, z - 1, y, x, Z, Y, X) + wprol(Wc, z + 1, y, x, Z, Y, X)
              + wprol(Wc, z, y - 1, x, Z, Y, X) + wprol(Wc, z, y + 1, x, Z, Y, X)
              + wprol(Wc, z, y, x - 1, Z, Y, X) + wprol(Wc, z, y, x + 1, Z, Y, X)
              - 6.f * wcn;
    int i = (z * Y + y) * X + x;
    out[i] = wcn - lap / DIAG + r[i] / DIAG;
}

// p1 at (possibly out-of-range -> clamped) coords: pointwise p-update of iter0
__device__ __forceinline__ float p1at(const float* __restrict__ pin,
                                      const float* __restrict__ D0,
                                      const float* __restrict__ r0,
                                      int z, int y, int x) {
    x = x < 0 ? 0 : (x > NX - 1 ? NX - 1 : x);
    y = y < 0 ? 0 : (y > NY - 1 ? NY - 1 : y);
    z = z < 0 ? 0 : (z > NZ - 1 ? NZ - 1 : z);
    int c = idx3(z, y, x);
    float wv = D0[(((z >> 1) * (NY >> 1)) + (y >> 1)) * (NX >> 1) + (x >> 1)];
    return pin[c] - wv + r0[c] / 6.0f;
}

// K8: iter0 p-update fused with iter1 residual.
// pIO holds b on entry (center read), p1 on exit.
__global__ __launch_bounds__(256) void k_pup_resid(
    const float* __restrict__ pin, const float* __restrict__ D0,
    const float* __restrict__ r0, float* __restrict__ pIO, float* __restrict__ r1res) {
    int x = threadIdx.x, y = blockIdx.x, z = blockIdx.y;
    int c = idx3(z, y, x);
    float bval = pIO[c];
    float p1c = p1at(pin, D0, r0, z, y, x);
    float lap = p1at(pin, D0, r0, z, y, x - 1) + p1at(pin, D0, r0, z, y, x + 1)
              + p1at(pin, D0, r0, z, y - 1, x) + p1at(pin, D0, r0, z, y + 1, x)
              + p1at(pin, D0, r0, z - 1, y, x) + p1at(pin, D0, r0, z + 1, y, x)
              - 6.f * p1c;
    r1res[c] = lap - bval;
    pIO[c] = p1c;
}

// K9: final p-update (iter1): p2 = p1 - prol(D1) + r1res/6; emit w_mg = prol(D1)
__global__ __launch_bounds__(256) void k_pup2(
    const float* __restrict__ D1, const float* __restrict__ r1res,
    float* __restrict__ pIO, float* __restrict__ wmg) {
    int x = threadIdx.x, y = blockIdx.x, z = blockIdx.y;
    int c = idx3(z, y, x);
    float wv = D1[(((z >> 1) * (NY >> 1)) + (y >> 1)) * (NX >> 1) + (x >> 1)];
    float p2 = pIO[c] - wv + r1res[c] / 6.0f;
    pIO[c] = p2;
    wmg[c] = wv;
}

// K10: projection + final solid_body
__global__ __launch_bounds__(256) void k_final(
    const float* __restrict__ p,
    const float* __restrict__ u2, const float* __restrict__ v2, const float* __restrict__ w2,
    const float* __restrict__ sg,
    float* __restrict__ uo, float* __restrict__ vo, float* __restrict__ wo) {
    int x = threadIdx.x, y = blockIdx.x, z = blockIdx.y;
    int c = idx3(z, y, x);
    float dpx = 0.5f * (ld_p(p, z, y, x + 1) - ld_p(p, z, y, x - 1));
    float dpy = 0.5f * (ld_p(p, z, y + 1, x) - ld_p(p, z, y - 1, x));
    float dpz = 0.5f * (ld_p(p, z + 1, y, x) - ld_p(p, z - 1, y, x));
    float inv = 1.f / (1.f + DT * sg[c]);
    uo[c] = (u2[c] - dpx * DT) * inv;
    vo[c] = (v2[c] - dpy * DT) * inv;
    wo[c] = (w2[c] - dpz * DT) * inv;
}

extern "C" void kernel_launch(void* const* d_in, const int* in_sizes, int n_in,
                              void* d_out, int out_size, void* d_ws, size_t ws_size,
                              hipStream_t stream) {
    const float* in_u  = (const float*)d_in[0];
    const float* in_v  = (const float*)d_in[1];
    const float* in_w  = (const float*)d_in[2];
    const float* in_p  = (const float*)d_in[3];
    const float* in_sg = (const float*)d_in[4];

    float* out   = (float*)d_out;
    float* O_u   = out;                      // bu -> r1res -> u_out
    float* O_v   = out + (size_t)NTOT;       // bv -> v_out
    float* O_w   = out + (size_t)2 * NTOT;   // bw -> w_out
    float* O_p   = out + (size_t)3 * NTOT;   // b  -> p1 -> p2
    float* O_wmg = out + (size_t)4 * NTOT;   // r0 -> wmg
    float* O_r   = out + (size_t)5 * NTOT;   // final coarsest residual (512)

    float* ws  = (float*)d_ws;
    float* A0  = ws;                          // u2
    float* A1  = ws + (size_t)NTOT;           // v2
    float* A2  = ws + (size_t)2 * NTOT;       // w2
    float* r1  = ws + (size_t)3 * NTOT;       // 262144
    float* r2  = r1 + 262144;                 // 32768
    float* r3  = r2 + 32768;                  // 4096
    float* r4w = r3 + 4096;                   // 512 (iter0 only)
    float* Cw  = r4w + 512;                   // 32768
    float* Dw  = Cw + 32768;                  // 262144

    dim3 gF(NY, NZ);
    dim3 bF(NX);
    dim3 gC(4, 4, 4);
    dim3 bC(512);

    k_predict <<<gF, bF, 0, stream>>>(in_u, in_v, in_w, in_p, in_sg, O_u, O_v, O_w);
    k_correct <<<gF, bF, 0, stream>>>(in_u, in_v, in_w, in_sg, O_u, O_v, O_w, in_p, A0, A1, A2);
    k_divresid<<<gF, bF, 0, stream>>>(A0, A1, A2, in_p, O_p /*b*/, O_wmg /*r0*/);

    // --- MG iteration 0 ---
    k_restrict<<<dim3(64, 32), dim3(128), 0, stream>>>(O_wmg, r1);
    k_cdown   <<<gC, bC, 0, stream>>>(r1, r2, r3, r4w);
    k_cup     <<<gC, bC, 0, stream>>>(r4w, r3, r2, Cw);
    k_up      <<<dim3(64, 32), dim3(128), 0, stream>>>(Cw, r1, Dw);
    k_pup_resid<<<gF, bF, 0, stream>>>(in_p, Dw, O_wmg, O_p /*b->p1*/, O_u /*r1res*/);

    // --- MG iteration 1 ---
    k_restrict<<<dim3(64, 32), dim3(128), 0, stream>>>(O_u, r1);
    k_cdown   <<<gC, bC, 0, stream>>>(r1, r2, r3, O_r);     // final coarsest residual
    k_cup     <<<gC, bC, 0, stream>>>(O_r, r3, r2, Cw);
    k_up      <<<dim3(64, 32), dim3(128), 0, stream>>>(Cw, r1, Dw);
    k_pup2    <<<gF, bF, 0, stream>>>(Dw, O_u /*r1res*/, O_p /*p1->p2*/, O_wmg /*wmg*/);

    k_final   <<<gF, bF, 0, stream>>>(O_p, A0, A1, A2, in_sg, O_u, O_v, O_w);
}

// Round 3
// 101.937 us; speedup vs baseline: 1.4294x; 1.2159x over previous
//
#include <hip/hip_runtime.h>

// ---------------------------------------------------------------------------
// AI4Urban one-timestep NS solver on 64x128x256, f32.  Round 3:
//  - float4 vectorization of all fine-grid kernels (each thread owns 4 x).
//  - b eliminated by linearity: r1res = r0 - lap_ep(prol(D0)) + lap_ep(r0)/6.
//  - restrict+coarse-down fused into one LDS kernel. 12 dispatches.
// ---------------------------------------------------------------------------

constexpr int NZ = 64, NY = 128, NX = 256;
constexpr int NTOT = NZ * NY * NX;
constexpr float DT  = 0.01f;
constexpr float RE  = 0.001f;
constexpr float UBC = -1.0f;
constexpr float DIAG = -6.0f;
constexpr float SIXTH = 1.0f / 6.0f;

__device__ __forceinline__ int idx3(int z, int y, int x) {
    return (z * NY + y) * NX + x;
}

union F4 { float4 v; float f[4]; };

__device__ __forceinline__ float4 ld4(const float* __restrict__ f, int z, int y, int x0) {
    return *reinterpret_cast<const float4*>(&f[idx3(z, y, x0)]);
}
__device__ __forceinline__ void st4(float* __restrict__ f, int c, const F4& a) {
    *reinterpret_cast<float4*>(&f[c]) = a.v;
}

// zero-filled row (bc 0 in y/z)
__device__ __forceinline__ void row0(const float* __restrict__ f, int z, int y, int x0,
                                     bool ok, float o[4]) {
    if (ok) { F4 a; a.v = ld4(f, z, y, x0);
        #pragma unroll
        for (int i = 0; i < 4; i++) o[i] = a.f[i];
    } else {
        #pragma unroll
        for (int i = 0; i < 4; i++) o[i] = 0.f;
    }
}
// solid-body-scaled row for three fields, zero-filled OOB
__device__ __forceinline__ void row3s(const float* __restrict__ u, const float* __restrict__ v,
                                      const float* __restrict__ w, const float* __restrict__ sg,
                                      int z, int y, int x0, bool ok,
                                      float uo[4], float vo[4], float wo[4]) {
    if (ok) {
        F4 a, b, c, s;
        a.v = ld4(u, z, y, x0); b.v = ld4(v, z, y, x0);
        c.v = ld4(w, z, y, x0); s.v = ld4(sg, z, y, x0);
        #pragma unroll
        for (int i = 0; i < 4; i++) {
            float iv = 1.f / (1.f + DT * s.f[i]);
            uo[i] = a.f[i] * iv; vo[i] = b.f[i] * iv; wo[i] = c.f[i] * iv;
        }
    } else {
        #pragma unroll
        for (int i = 0; i < 4; i++) { uo[i] = vo[i] = wo[i] = 0.f; }
    }
}

// scalar helpers (coarse kernels)
__device__ __forceinline__ float ld_p_s(const float* __restrict__ f, int z, int y, int x) {
    x = x < 0 ? 0 : (x > NX - 1 ? NX - 1 : x);
    y = y < 0 ? 0 : (y > NY - 1 ? NY - 1 : y);
    z = z < 0 ? 0 : (z > NZ - 1 ? NZ - 1 : z);
    return f[idx3(z, y, x)];
}

// K1: predictor, solid_body fused (u1 = u/(1+DT*sg) recomputed at stencil pts)
__global__ __launch_bounds__(256) void k_predict(
    const float* __restrict__ u, const float* __restrict__ v, const float* __restrict__ w,
    const float* __restrict__ p, const float* __restrict__ sg,
    float* __restrict__ bu, float* __restrict__ bv, float* __restrict__ bw) {
    int tx = threadIdx.x, y = blockIdx.x * 4 + threadIdx.y, z = blockIdx.y;
    int x0 = tx << 2, c = idx3(z, y, x0);

    F4 sc; sc.v = ld4(sg, z, y, x0);
    F4 u4, v4, w4; u4.v = ld4(u, z, y, x0); v4.v = ld4(v, z, y, x0); w4.v = ld4(w, z, y, x0);
    float inv[4], uc[4], vc[4], wc[4];
    #pragma unroll
    for (int i = 0; i < 4; i++) {
        inv[i] = 1.f / (1.f + DT * sc.f[i]);
        uc[i] = u4.f[i] * inv[i]; vc[i] = v4.f[i] * inv[i]; wc[i] = w4.f[i] * inv[i];
    }
    float uym[4], vym[4], wym[4], uyp[4], vyp[4], wyp[4];
    float uzm[4], vzm[4], wzm[4], uzp[4], vzp[4], wzp[4];
    row3s(u, v, w, sg, z, y - 1, x0, y > 0,      uym, vym, wym);
    row3s(u, v, w, sg, z, y + 1, x0, y < NY - 1, uyp, vyp, wyp);
    row3s(u, v, w, sg, z - 1, y, x0, z > 0,      uzm, vzm, wzm);
    row3s(u, v, w, sg, z + 1, y, x0, z < NZ - 1, uzp, vzp, wzp);

    float uxmS, vxmS, wxmS, uxpS, vxpS, wxpS;
    if (tx > 0) { float iv = 1.f / (1.f + DT * sg[c - 1]);
        uxmS = u[c - 1] * iv; vxmS = v[c - 1] * iv; wxmS = w[c - 1] * iv; }
    else { uxmS = UBC; vxmS = 0.f; wxmS = 0.f; }
    if (tx < 63) { float iv = 1.f / (1.f + DT * sg[c + 4]);
        uxpS = u[c + 4] * iv; vxpS = v[c + 4] * iv; wxpS = w[c + 4] * iv; }
    else { uxpS = vxpS = wxpS = 0.f; }

    F4 pc, pym, pyp, pzm, pzp;
    pc.v  = ld4(p, z, y, x0);
    pym.v = ld4(p, z, y > 0 ? y - 1 : 0, x0);
    pyp.v = ld4(p, z, y < NY - 1 ? y + 1 : y, x0);
    pzm.v = ld4(p, z > 0 ? z - 1 : 0, y, x0);
    pzp.v = ld4(p, z < NZ - 1 ? z + 1 : z, y, x0);
    float pxmS = tx ? p[c - 1] : pc.f[0];
    float pxpS = (tx < 63) ? p[c + 4] : pc.f[3];

    F4 obu, obv, obw;
    #pragma unroll
    for (int i = 0; i < 4; i++) {
        float uxm = i ? uc[i - 1] : uxmS, uxp = (i < 3) ? uc[i + 1] : uxpS;
        float vxm = i ? vc[i - 1] : vxmS, vxp = (i < 3) ? vc[i + 1] : vxpS;
        float wxm = i ? wc[i - 1] : wxmS, wxp = (i < 3) ? wc[i + 1] : wxpS;
        float pxm = i ? pc.f[i - 1] : pxmS, pxp = (i < 3) ? pc.f[i + 1] : pxpS;
        float dpx = 0.5f * (pxp - pxm);
        float dpy = 0.5f * (pyp.f[i] - pym.f[i]);
        float dpz = 0.5f * (pzp.f[i] - pzm.f[i]);
        float lap_u = uxm + uxp + uym[i] + uyp[i] + uzm[i] + uzp[i] - 6.f * uc[i];
        float lap_v = vxm + vxp + vym[i] + vyp[i] + vzm[i] + vzp[i] - 6.f * vc[i];
        float lap_w = wxm + wxp + wym[i] + wyp[i] + wzm[i] + wzp[i] - 6.f * wc[i];
        float bun = uc[i] + 0.5f * (RE * lap_u * DT
                    - uc[i] * (0.5f * (uxp - uxm)) * DT
                    - vc[i] * (0.5f * (uyp[i] - uym[i])) * DT
                    - wc[i] * (0.5f * (uzp[i] - uzm[i])) * DT) - dpx * DT;
        float bvn = vc[i] + 0.5f * (RE * lap_v * DT
                    - uc[i] * (0.5f * (vxp - vxm)) * DT
                    - vc[i] * (0.5f * (vyp[i] - vym[i])) * DT
                    - wc[i] * (0.5f * (vzp[i] - vzm[i])) * DT) - dpy * DT;
        float bwn = wc[i] + 0.5f * (RE * lap_w * DT
                    - uc[i] * (0.5f * (wxp - wxm)) * DT
                    - vc[i] * (0.5f * (wyp[i] - wym[i])) * DT
                    - wc[i] * (0.5f * (wzp[i] - wzm[i])) * DT) - dpz * DT;
        obu.f[i] = bun * inv[i];
        obv.f[i] = bvn * inv[i];
        obw.f[i] = bwn * inv[i];
    }
    st4(bu, c, obu); st4(bv, c, obv); st4(bw, c, obw);
}

// K2: corrector
__global__ __launch_bounds__(256) void k_correct(
    const float* __restrict__ u, const float* __restrict__ v, const float* __restrict__ w,
    const float* __restrict__ sg,
    const float* __restrict__ bu, const float* __restrict__ bv, const float* __restrict__ bw,
    const float* __restrict__ p,
    float* __restrict__ u2, float* __restrict__ v2, float* __restrict__ w2) {
    int tx = threadIdx.x, y = blockIdx.x * 4 + threadIdx.y, z = blockIdx.y;
    int x0 = tx << 2, c = idx3(z, y, x0);

    F4 sc; sc.v = ld4(sg, z, y, x0);
    F4 u4, v4, w4; u4.v = ld4(u, z, y, x0); v4.v = ld4(v, z, y, x0); w4.v = ld4(w, z, y, x0);
    F4 buc, bvc, bwc; buc.v = ld4(bu, z, y, x0); bvc.v = ld4(bv, z, y, x0); bwc.v = ld4(bw, z, y, x0);

    float uym[4], vym[4], wym[4], uyp[4], vyp[4], wyp[4];
    float uzm[4], vzm[4], wzm[4], uzp[4], vzp[4], wzp[4];
    row0(bu, z, y - 1, x0, y > 0, uym);      row0(bv, z, y - 1, x0, y > 0, vym);
    row0(bw, z, y - 1, x0, y > 0, wym);
    row0(bu, z, y + 1, x0, y < NY - 1, uyp); row0(bv, z, y + 1, x0, y < NY - 1, vyp);
    row0(bw, z, y + 1, x0, y < NY - 1, wyp);
    row0(bu, z - 1, y, x0, z > 0, uzm);      row0(bv, z - 1, y, x0, z > 0, vzm);
    row0(bw, z - 1, y, x0, z > 0, wzm);
    row0(bu, z + 1, y, x0, z < NZ - 1, uzp); row0(bv, z + 1, y, x0, z < NZ - 1, vzp);
    row0(bw, z + 1, y, x0, z < NZ - 1, wzp);

    float uxmS = tx ? bu[c - 1] : UBC,  uxpS = (tx < 63) ? bu[c + 4] : 0.f;
    float vxmS = tx ? bv[c - 1] : 0.f,  vxpS = (tx < 63) ? bv[c + 4] : 0.f;
    float wxmS = tx ? bw[c - 1] : 0.f,  wxpS = (tx < 63) ? bw[c + 4] : 0.f;

    F4 pc, pym, pyp, pzm, pzp;
    pc.v  = ld4(p, z, y, x0);
    pym.v = ld4(p, z, y > 0 ? y - 1 : 0, x0);
    pyp.v = ld4(p, z, y < NY - 1 ? y + 1 : y, x0);
    pzm.v = ld4(p, z > 0 ? z - 1 : 0, y, x0);
    pzp.v = ld4(p, z < NZ - 1 ? z + 1 : z, y, x0);
    float pxmS = tx ? p[c - 1] : pc.f[0];
    float pxpS = (tx < 63) ? p[c + 4] : pc.f[3];

    F4 ou, ov, ow;
    #pragma unroll
    for (int i = 0; i < 4; i++) {
        float inv = 1.f / (1.f + DT * sc.f[i]);
        float u1c = u4.f[i] * inv, v1c = v4.f[i] * inv, w1c = w4.f[i] * inv;
        float uxm = i ? buc.f[i - 1] : uxmS, uxp = (i < 3) ? buc.f[i + 1] : uxpS;
        float vxm = i ? bvc.f[i - 1] : vxmS, vxp = (i < 3) ? bvc.f[i + 1] : vxpS;
        float wxm = i ? bwc.f[i - 1] : wxmS, wxp = (i < 3) ? bwc.f[i + 1] : wxpS;
        float pxm = i ? pc.f[i - 1] : pxmS, pxp = (i < 3) ? pc.f[i + 1] : pxpS;
        float dpx = 0.5f * (pxp - pxm);
        float dpy = 0.5f * (pyp.f[i] - pym.f[i]);
        float dpz = 0.5f * (pzp.f[i] - pzm.f[i]);
        float lap_u = uxm + uxp + uym[i] + uyp[i] + uzm[i] + uzp[i] - 6.f * buc.f[i];
        float lap_v = vxm + vxp + vym[i] + vyp[i] + vzm[i] + vzp[i] - 6.f * bvc.f[i];
        float lap_w = wxm + wxp + wym[i] + wyp[i] + wzm[i] + wzp[i] - 6.f * bwc.f[i];
        float un = u1c + RE * lap_u * DT
                   - buc.f[i] * (0.5f * (uxp - uxm)) * DT
                   - bvc.f[i] * (0.5f * (uyp[i] - uym[i])) * DT
                   - bwc.f[i] * (0.5f * (uzp[i] - uzm[i])) * DT - dpx * DT;
        float vn = v1c + RE * lap_v * DT
                   - buc.f[i] * (0.5f * (vxp - vxm)) * DT
                   - bvc.f[i] * (0.5f * (vyp[i] - vym[i])) * DT
                   - bwc.f[i] * (0.5f * (vzp[i] - vzm[i])) * DT - dpy * DT;
        float wn = w1c + RE * lap_w * DT
                   - buc.f[i] * (0.5f * (wxp - wxm)) * DT
                   - bvc.f[i] * (0.5f * (wyp[i] - wym[i])) * DT
                   - bwc.f[i] * (0.5f * (wzp[i] - wzm[i])) * DT - dpz * DT;
        ou.f[i] = un * inv; ov.f[i] = vn * inv; ow.f[i] = wn * inv;
    }
    st4(u2, c, ou); st4(v2, c, ov); st4(w2, c, ow);
}

// K3: r0 = lap_ep(p) - b, with b = -div(vel)/DT computed inline (b never stored)
__global__ __launch_bounds__(256) void k_divresid(
    const float* __restrict__ u2, const float* __restrict__ v2, const float* __restrict__ w2,
    const float* __restrict__ p, float* __restrict__ r0) {
    int tx = threadIdx.x, y = blockIdx.x * 4 + threadIdx.y, z = blockIdx.y;
    int x0 = tx << 2, c = idx3(z, y, x0);

    F4 uc; uc.v = ld4(u2, z, y, x0);
    float uxmS = tx ? u2[c - 1] : UBC, uxpS = (tx < 63) ? u2[c + 4] : 0.f;
    float vym[4], vyp[4], wzm[4], wzp[4];
    row0(v2, z, y - 1, x0, y > 0, vym);
    row0(v2, z, y + 1, x0, y < NY - 1, vyp);
    row0(w2, z - 1, y, x0, z > 0, wzm);
    row0(w2, z + 1, y, x0, z < NZ - 1, wzp);

    F4 pc, pym, pyp, pzm, pzp;
    pc.v  = ld4(p, z, y, x0);
    pym.v = ld4(p, z, y > 0 ? y - 1 : 0, x0);
    pyp.v = ld4(p, z, y < NY - 1 ? y + 1 : y, x0);
    pzm.v = ld4(p, z > 0 ? z - 1 : 0, y, x0);
    pzp.v = ld4(p, z < NZ - 1 ? z + 1 : z, y, x0);
    float pxmS = tx ? p[c - 1] : pc.f[0];
    float pxpS = (tx < 63) ? p[c + 4] : pc.f[3];

    F4 o;
    #pragma unroll
    for (int i = 0; i < 4; i++) {
        float uxm = i ? uc.f[i - 1] : uxmS, uxp = (i < 3) ? uc.f[i + 1] : uxpS;
        float bval = -(0.5f * (uxp - uxm) + 0.5f * (vyp[i] - vym[i])
                       + 0.5f * (wzp[i] - wzm[i])) / DT;
        float pxm = i ? pc.f[i - 1] : pxmS, pxp = (i < 3) ? pc.f[i + 1] : pxpS;
        float lap = pxm + pxp + pym.f[i] + pyp.f[i] + pzm.f[i] + pzp.f[i] - 6.f * pc.f[i];
        o.f[i] = lap - bval;
    }
    st4(r0, c, o);
}

// K4: fused restrict chain: fine(64,128,256) -> r1(32,64,128) -> r2 -> r3 -> r4
__global__ __launch_bounds__(512) void k_rescdown(const float* __restrict__ rf,
    float* __restrict__ r1, float* __restrict__ r2, float* __restrict__ r3,
    float* __restrict__ r4) {
    __shared__ float l1[8][16][32];
    __shared__ float l2[4][8][16];
    __shared__ float l3[2][4][8];
    int tid = threadIdx.x;
    int bx = blockIdx.x, by = blockIdx.y, bz = blockIdx.z;
    int lx = tid & 31, ly = (tid >> 5) & 15;
    int x1 = bx * 32 + lx, y1 = by * 16 + ly;
    #pragma unroll
    for (int lz = 0; lz < 8; lz++) {
        int z1 = bz * 8 + lz;
        const float* b0 = &rf[idx3(2 * z1, 2 * y1, 2 * x1)];
        float2 a  = *reinterpret_cast<const float2*>(b0);
        float2 bq = *reinterpret_cast<const float2*>(b0 + NX);
        float2 cq = *reinterpret_cast<const float2*>(b0 + NY * NX);
        float2 dq = *reinterpret_cast<const float2*>(b0 + NY * NX + NX);
        float val = 0.125f * (a.x + a.y + bq.x + bq.y + cq.x + cq.y + dq.x + dq.y);
        l1[lz][ly][lx] = val;
        r1[((z1 * 64) + y1) * 128 + x1] = val;
    }
    __syncthreads();
    {
        int tx2 = tid & 15, ty2 = (tid >> 4) & 7, tz2 = tid >> 7;
        float s = l1[2*tz2][2*ty2][2*tx2]     + l1[2*tz2][2*ty2][2*tx2+1]
                + l1[2*tz2][2*ty2+1][2*tx2]   + l1[2*tz2][2*ty2+1][2*tx2+1]
                + l1[2*tz2+1][2*ty2][2*tx2]   + l1[2*tz2+1][2*ty2][2*tx2+1]
                + l1[2*tz2+1][2*ty2+1][2*tx2] + l1[2*tz2+1][2*ty2+1][2*tx2+1];
        float val = 0.125f * s;
        l2[tz2][ty2][tx2] = val;
        int x2 = bx * 16 + tx2, y2 = by * 8 + ty2, z2 = bz * 4 + tz2;
        r2[((z2 * 32) + y2) * 64 + x2] = val;
    }
    __syncthreads();
    if (tid < 64) {
        int tx3 = tid & 7, ty3 = (tid >> 3) & 3, tz3 = tid >> 5;
        float s = l2[2*tz3][2*ty3][2*tx3]     + l2[2*tz3][2*ty3][2*tx3+1]
                + l2[2*tz3][2*ty3+1][2*tx3]   + l2[2*tz3][2*ty3+1][2*tx3+1]
                + l2[2*tz3+1][2*ty3][2*tx3]   + l2[2*tz3+1][2*ty3][2*tx3+1]
                + l2[2*tz3+1][2*ty3+1][2*tx3] + l2[2*tz3+1][2*ty3+1][2*tx3+1];
        float val = 0.125f * s;
        l3[tz3][ty3][tx3] = val;
        int x3 = bx * 8 + tx3, y3 = by * 4 + ty3, z3 = bz * 2 + tz3;
        r3[((z3 * 16) + y3) * 32 + x3] = val;
    }
    __syncthreads();
    if (tid < 8) {
        int tx4 = tid & 3, ty4 = tid >> 2;
        float s = l3[0][2*ty4][2*tx4]   + l3[0][2*ty4][2*tx4+1]
                + l3[0][2*ty4+1][2*tx4] + l3[0][2*ty4+1][2*tx4+1]
                + l3[1][2*ty4][2*tx4]   + l3[1][2*ty4][2*tx4+1]
                + l3[1][2*ty4+1][2*tx4] + l3[1][2*ty4+1][2*tx4+1];
        int x4 = bx * 4 + tx4, y4 = by * 2 + ty4, z4 = bz;
        r4[((z4 * 8) + y4) * 16 + x4] = 0.125f * s;
    }
}

// prolonged-A read with bc_cw zero at level-3 bounds; A = r4/diag
__device__ __forceinline__ float a4p(const float* __restrict__ r4, int z3, int y3, int x3) {
    if ((unsigned)z3 >= 8u || (unsigned)y3 >= 16u || (unsigned)x3 >= 32u) return 0.f;
    return r4[(((z3 >> 1) * 8) + (y3 >> 1)) * 16 + (x3 >> 1)] / DIAG;
}

// K5: fused coarse up-chain: A=r4/diag -> B(8,16,32) in LDS -> C(16,32,64)
__global__ __launch_bounds__(512) void k_cup(const float* __restrict__ r4,
    const float* __restrict__ r3, const float* __restrict__ r2, float* __restrict__ C) {
    __shared__ float Bl[4][6][10];
    int tid = threadIdx.x;
    int bx = blockIdx.x, by = blockIdx.y, bz = blockIdx.z;
    int Bz0 = bz * 2 - 1, By0 = by * 4 - 1, Bx0 = bx * 8 - 1;
    if (tid < 240) {
        int lx = tid % 10, ly = (tid / 10) % 6, lz = tid / 60;
        int z3 = Bz0 + lz, y3 = By0 + ly, x3 = Bx0 + lx;
        float val = 0.f;
        if ((unsigned)z3 < 8u && (unsigned)y3 < 16u && (unsigned)x3 < 32u) {
            float wcn = r4[(((z3 >> 1) * 8) + (y3 >> 1)) * 16 + (x3 >> 1)] / DIAG;
            float lap = a4p(r4, z3 - 1, y3, x3) + a4p(r4, z3 + 1, y3, x3)
                      + a4p(r4, z3, y3 - 1, x3) + a4p(r4, z3, y3 + 1, x3)
                      + a4p(r4, z3, y3, x3 - 1) + a4p(r4, z3, y3, x3 + 1) - 6.f * wcn;
            val = wcn - lap / DIAG + r3[((z3 * 16) + y3) * 32 + x3] / DIAG;
        }
        Bl[lz][ly][lx] = val;
    }
    __syncthreads();
    int tx = tid & 15, ty = (tid >> 4) & 7, tz = tid >> 7;
    int x2 = bx * 16 + tx, y2 = by * 8 + ty, z2 = bz * 4 + tz;
    auto bl = [&](int z, int y, int x) -> float {
        if ((unsigned)z >= 16u || (unsigned)y >= 32u || (unsigned)x >= 64u) return 0.f;
        return Bl[(z >> 1) - Bz0][(y >> 1) - By0][(x >> 1) - Bx0];
    };
    float wB = Bl[(z2 >> 1) - Bz0][(y2 >> 1) - By0][(x2 >> 1) - Bx0];
    float lap = bl(z2 - 1, y2, x2) + bl(z2 + 1, y2, x2)
              + bl(z2, y2 - 1, x2) + bl(z2, y2 + 1, x2)
              + bl(z2, y2, x2 - 1) + bl(z2, y2, x2 + 1) - 6.f * wB;
    int i = ((z2 * 32) + y2) * 64 + x2;
    C[i] = wB - lap / DIAG + r2[i] / DIAG;
}

// K6: level-1 up (dims X=128,Y=64,Z=32 from launch config)
__device__ __forceinline__ float wprol(const float* __restrict__ Wc,
                                       int zz, int yy, int xx, int Z, int Y, int X) {
    if ((unsigned)xx >= (unsigned)X || (unsigned)yy >= (unsigned)Y || (unsigned)zz >= (unsigned)Z) return 0.f;
    return Wc[(((zz >> 1) * (Y >> 1)) + (yy >> 1)) * (X >> 1) + (xx >> 1)];
}
__global__ void k_up(const float* __restrict__ Wc, const float* __restrict__ r,
                     float* __restrict__ out) {
    int X = blockDim.x, Y = gridDim.x, Z = gridDim.y;
    int x = threadIdx.x, y = blockIdx.x, z = blockIdx.y;
    float wcn = Wc[(((z >> 1) * (Y >> 1)) + (y >> 1)) * (X >> 1) + (x >> 1)];
    float lap = wprol(Wc, z - 1, y, x, Z, Y, X) + wprol(Wc, z + 1, y, x, Z, Y, X)
              + wprol(Wc, z, y - 1, x, Z, Y, X) + wprol(Wc, z, y + 1, x, Z, Y, X)
              + wprol(Wc, z, y, x - 1, Z, Y, X) + wprol(Wc, z, y, x + 1, Z, Y, X)
              - 6.f * wcn;
    int i = (z * Y + y) * X + x;
    out[i] = wcn - lap / DIAG + r[i] / DIAG;
}

// K7: iter0 p-update + iter1 residual via linearity:
//   p1 = pin - prol(D0) + r0/6
//   r1res = r0 - lap_ep(prol(D0)) + lap_ep(r0)/6
__global__ __launch_bounds__(256) void k_pup_resid(
    const float* __restrict__ pin, const float* __restrict__ D0,
    const float* __restrict__ r0, float* __restrict__ p1, float* __restrict__ r1res) {
    int tx = threadIdx.x, y = blockIdx.x * 4 + threadIdx.y, z = blockIdx.y;
    int x0 = tx << 2, c = idx3(z, y, x0);
    int cz = z >> 1, cy = y >> 1, cx0 = tx << 1;

    const float* Drow = &D0[(cz * 64 + cy) * 128];
    float cr[4];
    cr[1] = Drow[cx0]; cr[2] = Drow[cx0 + 1];
    cr[0] = tx ? Drow[cx0 - 1] : cr[1];
    cr[3] = (tx < 63) ? Drow[cx0 + 2] : cr[2];
    int cym = y ? (y - 1) >> 1 : 0, cyp = (y < NY - 1) ? (y + 1) >> 1 : cy;
    int czm = z ? (z - 1) >> 1 : 0, czp = (z < NZ - 1) ? (z + 1) >> 1 : cz;
    float2 dym = *reinterpret_cast<const float2*>(&D0[(cz * 64 + cym) * 128 + cx0]);
    float2 dyp = *reinterpret_cast<const float2*>(&D0[(cz * 64 + cyp) * 128 + cx0]);
    float2 dzm = *reinterpret_cast<const float2*>(&D0[(czm * 64 + cy) * 128 + cx0]);
    float2 dzp = *reinterpret_cast<const float2*>(&D0[(czp * 64 + cy) * 128 + cx0]);

    F4 rc, rym, ryp, rzm, rzp, pin4;
    rc.v  = ld4(r0, z, y, x0);
    rym.v = ld4(r0, z, y > 0 ? y - 1 : 0, x0);
    ryp.v = ld4(r0, z, y < NY - 1 ? y + 1 : y, x0);
    rzm.v = ld4(r0, z > 0 ? z - 1 : 0, y, x0);
    rzp.v = ld4(r0, z < NZ - 1 ? z + 1 : z, y, x0);
    pin4.v = ld4(pin, z, y, x0);
    float rxmS = tx ? r0[c - 1] : rc.f[0];
    float rxpS = (tx < 63) ? r0[c + 4] : rc.f[3];

    F4 op1, ores;
    #pragma unroll
    for (int i = 0; i < 4; i++) {
        float Dc  = cr[1 + (i >> 1)];
        float Dxm = (i == 0) ? cr[0] : cr[1 + ((i - 1) >> 1)];
        float Dxp = (i == 3) ? cr[3] : cr[1 + ((i + 1) >> 1)];
        float Dym = (i < 2) ? dym.x : dym.y;
        float Dyp = (i < 2) ? dyp.x : dyp.y;
        float Dzm = (i < 2) ? dzm.x : dzm.y;
        float Dzp = (i < 2) ? dzp.x : dzp.y;
        float lapD = Dxm + Dxp + Dym + Dyp + Dzm + Dzp - 6.f * Dc;
        float rxm = i ? rc.f[i - 1] : rxmS, rxp = (i < 3) ? rc.f[i + 1] : rxpS;
        float lapR = rxm + rxp + rym.f[i] + ryp.f[i] + rzm.f[i] + rzp.f[i] - 6.f * rc.f[i];
        op1.f[i]  = pin4.f[i] - Dc + rc.f[i] * SIXTH;
        ores.f[i] = rc.f[i] - lapD + lapR * SIXTH;
    }
    st4(p1, c, op1); st4(r1res, c, ores);
}

// K8: final p-update: p2 = p1 - prol(D1) + r1res/6 ; wmg = prol(D1)
__global__ __launch_bounds__(256) void k_pup2(
    const float* __restrict__ D1, const float* __restrict__ r1res,
    float* __restrict__ pIO, float* __restrict__ wmg) {
    int tx = threadIdx.x, y = blockIdx.x * 4 + threadIdx.y, z = blockIdx.y;
    int x0 = tx << 2, c = idx3(z, y, x0);
    int cz = z >> 1, cy = y >> 1, cx0 = tx << 1;
    float2 d2 = *reinterpret_cast<const float2*>(&D1[(cz * 64 + cy) * 128 + cx0]);
    F4 rr, pp; rr.v = ld4(r1res, z, y, x0); pp.v = ld4(pIO, z, y, x0);
    F4 op, ow;
    #pragma unroll
    for (int i = 0; i < 4; i++) {
        float wv = (i < 2) ? d2.x : d2.y;
        op.f[i] = pp.f[i] - wv + rr.f[i] * SIXTH;
        ow.f[i] = wv;
    }
    st4(pIO, c, op); st4(wmg, c, ow);
}

// K9: projection + final solid_body
__global__ __launch_bounds__(256) void k_final(
    const float* __restrict__ p,
    const float* __restrict__ u2, const float* __restrict__ v2, const float* __restrict__ w2,
    const float* __restrict__ sg,
    float* __restrict__ uo, float* __restrict__ vo, float* __restrict__ wo) {
    int tx = threadIdx.x, y = blockIdx.x * 4 + threadIdx.y, z = blockIdx.y;
    int x0 = tx << 2, c = idx3(z, y, x0);
    F4 pc, pym, pyp, pzm, pzp;
    pc.v  = ld4(p, z, y, x0);
    pym.v = ld4(p, z, y > 0 ? y - 1 : 0, x0);
    pyp.v = ld4(p, z, y < NY - 1 ? y + 1 : y, x0);
    pzm.v = ld4(p, z > 0 ? z - 1 : 0, y, x0);
    pzp.v = ld4(p, z < NZ - 1 ? z + 1 : z, y, x0);
    float pxmS = tx ? p[c - 1] : pc.f[0];
    float pxpS = (tx < 63) ? p[c + 4] : pc.f[3];
    F4 sc; sc.v = ld4(sg, z, y, x0);
    F4 a, b, cc; a.v = ld4(u2, z, y, x0); b.v = ld4(v2, z, y, x0); cc.v = ld4(w2, z, y, x0);
    F4 ou, ov, ow;
    #pragma unroll
    for (int i = 0; i < 4; i++) {
        float pxm = i ? pc.f[i - 1] : pxmS, pxp = (i < 3) ? pc.f[i + 1] : pxpS;
        float inv = 1.f / (1.f + DT * sc.f[i]);
        ou.f[i] = (a.f[i]  - 0.5f * (pxp - pxm) * DT) * inv;
        ov.f[i] = (b.f[i]  - 0.5f * (pyp.f[i] - pym.f[i]) * DT) * inv;
        ow.f[i] = (cc.f[i] - 0.5f * (pzp.f[i] - pzm.f[i]) * DT) * inv;
    }
    st4(uo, c, ou); st4(vo, c, ov); st4(wo, c, ow);
}

extern "C" void kernel_launch(void* const* d_in, const int* in_sizes, int n_in,
                              void* d_out, int out_size, void* d_ws, size_t ws_size,
                              hipStream_t stream) {
    const float* in_u  = (const float*)d_in[0];
    const float* in_v  = (const float*)d_in[1];
    const float* in_w  = (const float*)d_in[2];
    const float* in_p  = (const float*)d_in[3];
    const float* in_sg = (const float*)d_in[4];

    float* out   = (float*)d_out;
    float* O_u   = out;                      // bu -> r1res -> u_out
    float* O_v   = out + (size_t)NTOT;       // bv -> v_out
    float* O_w   = out + (size_t)2 * NTOT;   // bw -> w_out
    float* O_p   = out + (size_t)3 * NTOT;   // p1 -> p2
    float* O_wmg = out + (size_t)4 * NTOT;   // r0 -> wmg
    float* O_r   = out + (size_t)5 * NTOT;   // final coarsest residual (512)

    float* ws  = (float*)d_ws;
    float* A0  = ws;                          // u2
    float* A1  = ws + (size_t)NTOT;           // v2
    float* A2  = ws + (size_t)2 * NTOT;       // w2
    float* r1  = ws + (size_t)3 * NTOT;       // 262144
    float* r2  = r1 + 262144;                 // 32768
    float* r3  = r2 + 32768;                  // 4096
    float* r4w = r3 + 4096;                   // 512
    float* Cw  = r4w + 512;                   // 32768
    float* Dw  = Cw + 32768;                  // 262144

    dim3 gF(NY / 4, NZ);
    dim3 bF(64, 4);
    dim3 gC(4, 4, 4);

    k_predict  <<<gF, bF, 0, stream>>>(in_u, in_v, in_w, in_p, in_sg, O_u, O_v, O_w);
    k_correct  <<<gF, bF, 0, stream>>>(in_u, in_v, in_w, in_sg, O_u, O_v, O_w, in_p, A0, A1, A2);
    k_divresid <<<gF, bF, 0, stream>>>(A0, A1, A2, in_p, O_wmg /*r0*/);

    // --- MG iteration 0 ---
    k_rescdown <<<gC, dim3(512), 0, stream>>>(O_wmg, r1, r2, r3, r4w);
    k_cup      <<<gC, dim3(512), 0, stream>>>(r4w, r3, r2, Cw);
    k_up       <<<dim3(64, 32), dim3(128), 0, stream>>>(Cw, r1, Dw);
    k_pup_resid<<<gF, bF, 0, stream>>>(in_p, Dw, O_wmg, O_p /*p1*/, O_u /*r1res*/);

    // --- MG iteration 1 ---
    k_rescdown <<<gC, dim3(512), 0, stream>>>(O_u, r1, r2, r3, O_r);
    k_cup      <<<gC, dim3(512), 0, stream>>>(O_r, r3, r2, Cw);
    k_up       <<<dim3(64, 32), dim3(128), 0, stream>>>(Cw, r1, Dw);
    k_pup2     <<<gF, bF, 0, stream>>>(Dw, O_u /*r1res*/, O_p /*p1->p2*/, O_wmg /*wmg*/);

    k_final    <<<gF, bF, 0, stream>>>(O_p, A0, A1, A2, in_sg, O_u, O_v, O_w);
}